// Round 9
// baseline (1153.617 us; speedup 1.0000x reference)
//
#include <hip/hip_runtime.h>

typedef short short8 __attribute__((ext_vector_type(8)));
typedef __bf16 bf16x8 __attribute__((ext_vector_type(8)));
typedef float f32x4 __attribute__((ext_vector_type(4)));

#define FEAT 128
#define FPL 2048

__device__ __forceinline__ float b2f(unsigned int u) {
  union { unsigned int u; float f; } c; c.u = u << 16; return c.f;
}
__device__ __forceinline__ unsigned short f2b(float f) {
  union { float f; unsigned int u; } c; c.f = f;
  unsigned int r = c.u + 0x7fffu + ((c.u >> 16) & 1u);
  return (unsigned short)(r >> 16);
}
__device__ __forceinline__ f32x4 mfma16(short8 a, short8 b, f32x4 c) {
  return __builtin_amdgcn_mfma_f32_16x16x32_bf16(
      __builtin_bit_cast(bf16x8, a), __builtin_bit_cast(bf16x8, b), c, 0, 0, 0);
}

// ---- conversion kernels ----
__global__ void cvt_kernel(const float* __restrict__ in, unsigned short* __restrict__ out, int n2) {
  int i = blockIdx.x * 256 + threadIdx.x;
  if (i < n2) {
    float2 v = ((const float2*)in)[i];
    unsigned int lo = f2b(v.x), hi = f2b(v.y);
    ((unsigned int*)out)[i] = lo | (hi << 16);
  }
}

// W[K][N] (row-major) -> WT[N][K] bf16
__global__ void cvtT_kernel(const float* __restrict__ W, unsigned short* __restrict__ WT, int K, int N) {
  int i = blockIdx.x * 256 + threadIdx.x;
  if (i < K * N) {
    int k = i / N, c = i - k * N;
    WT[(size_t)c * K + k] = f2b(W[i]);
  }
}

// ---- CSR build ----
__global__ void count_kernel(const int* __restrict__ dst, int* __restrict__ cnt, int n) {
  int i = blockIdx.x * 256 + threadIdx.x;
  if (i < n) atomicAdd(&cnt[dst[i]], 1);
}

// hierarchical exclusive scan: scan1 (per-1024 chunk) -> scan2 (chunk sums) -> scan3 (add offsets)
__global__ __launch_bounds__(1024) void scan1_kernel(const int* __restrict__ cnt,
    int* __restrict__ ex, int* __restrict__ chunkSum, int n) {
  __shared__ int sd[1024];
  const int i = blockIdx.x * 1024 + threadIdx.x;
  int v = (i < n) ? cnt[i] : 0;
  sd[threadIdx.x] = v;
  __syncthreads();
  int sum = v;
  for (int off = 1; off < 1024; off <<= 1) {
    int t = (threadIdx.x >= (unsigned)off) ? sd[threadIdx.x - off] : 0;
    __syncthreads();
    sum += t;
    sd[threadIdx.x] = sum;
    __syncthreads();
  }
  if (i < n) ex[i] = sum - v;
  if (threadIdx.x == 1023) chunkSum[blockIdx.x] = sum;
}

__global__ __launch_bounds__(1024) void scan2_kernel(const int* __restrict__ chunkSum,
    int* __restrict__ chunkOff, int nChunks) {
  __shared__ int sd[1024];
  int v = (threadIdx.x < (unsigned)nChunks) ? chunkSum[threadIdx.x] : 0;
  sd[threadIdx.x] = v;
  __syncthreads();
  int sum = v;
  for (int off = 1; off < 1024; off <<= 1) {
    int t = (threadIdx.x >= (unsigned)off) ? sd[threadIdx.x - off] : 0;
    __syncthreads();
    sum += t;
    sd[threadIdx.x] = sum;
    __syncthreads();
  }
  if (threadIdx.x < (unsigned)nChunks) chunkOff[threadIdx.x] = sum - v;
}

__global__ void scan3_kernel(const int* __restrict__ ex, const int* __restrict__ chunkOff,
    const int* __restrict__ chunkSum, int* __restrict__ rp, int n, int nChunks) {
  int i = blockIdx.x * 256 + threadIdx.x;
  if (i < n) rp[i] = ex[i] + chunkOff[i >> 10];
  if (i == 0) rp[n] = chunkOff[nChunks - 1] + chunkSum[nChunks - 1];
}

__global__ void copy_kernel(const int* __restrict__ a, int* __restrict__ b, int n) {
  int i = blockIdx.x * 256 + threadIdx.x;
  if (i < n) b[i] = a[i];
}

__global__ void initb_kernel(const int* __restrict__ rp, int* __restrict__ bcur, int nBuckets) {
  int b = blockIdx.x * 256 + threadIdx.x;
  if (b < nBuckets) bcur[b] = rp[b << 6];
}

// Two-phase binned CSR fill. Round-8 profile: direct col scatter wrote 100 MB
// HBM (4B random stores across 6.4MB from 8 XCDs -> line ping-pong). Phase A
// scatters 8B (src,dst) pairs into the dst-bucket's contiguous CSR region
// (~782 hot lines, L2-resident); phase B reads pairs sequentially and places
// col within the same ~8KB region -> localized writes.
__global__ void binA_kernel(const int* __restrict__ src, const int* __restrict__ dst,
                            int* __restrict__ bcur, int2* __restrict__ pair, int n) {
  int i = blockIdx.x * 256 + threadIdx.x;
  if (i < n) {
    int d = dst[i];
    int p = atomicAdd(&bcur[d >> 6], 1);
    pair[p] = make_int2(src[i], d);
  }
}

__global__ void binB_kernel(const int2* __restrict__ pair, int* __restrict__ cursor,
                            int* __restrict__ col, int n) {
  int i = blockIdx.x * 256 + threadIdx.x;
  if (i < n) {
    int2 pr = pair[i];
    int p = atomicAdd(&cursor[pr.y], 1);
    col[p] = pr.x;
  }
}

// ---- neighbor gather: agg[i] = x[i] + sum_{j in N(i)} x[j], bf16 in/out, fp32 accum ----
// One wave per atom; lane halves (32+32) process 2 edges per iteration with 8B
// loads (dwordx2), combined at the end via shfl_xor(32).
__global__ __launch_bounds__(256) void gather_kernel(const unsigned short* __restrict__ x,
    const int* __restrict__ rp, const int* __restrict__ col,
    unsigned short* __restrict__ agg, int n) {
  int wid = (blockIdx.x * 256 + threadIdx.x) >> 6;
  int lane = threadIdx.x & 63;
  if (wid >= n) return;
  const int half = lane >> 5;
  const int l32 = lane & 31;
  const unsigned long long* xq = (const unsigned long long*)x;  // 8B = 4 bf16

  float a0, a1, a2, a3;
  {
    unsigned long long sv = xq[(size_t)wid * 32 + l32];
    if (half == 0) {
      a0 = b2f((unsigned int)(sv & 0xffffu));
      a1 = b2f((unsigned int)((sv >> 16) & 0xffffu));
      a2 = b2f((unsigned int)((sv >> 32) & 0xffffu));
      a3 = b2f((unsigned int)((sv >> 48) & 0xffffu));
    } else {
      a0 = a1 = a2 = a3 = 0.f;
    }
  }
  const int beg = rp[wid], end = rp[wid + 1];
  int j = beg;
  for (; j + 4 <= end; j += 4) {
    int c0 = col[j + half];
    int c1 = col[j + 2 + half];
    unsigned long long v0 = xq[(size_t)c0 * 32 + l32];
    unsigned long long v1 = xq[(size_t)c1 * 32 + l32];
    a0 += b2f((unsigned int)(v0 & 0xffffu)) + b2f((unsigned int)(v1 & 0xffffu));
    a1 += b2f((unsigned int)((v0 >> 16) & 0xffffu)) + b2f((unsigned int)((v1 >> 16) & 0xffffu));
    a2 += b2f((unsigned int)((v0 >> 32) & 0xffffu)) + b2f((unsigned int)((v1 >> 32) & 0xffffu));
    a3 += b2f((unsigned int)((v0 >> 48) & 0xffffu)) + b2f((unsigned int)((v1 >> 48) & 0xffffu));
  }
  if (j + 2 <= end) {
    int c0 = col[j + half];
    unsigned long long v0 = xq[(size_t)c0 * 32 + l32];
    a0 += b2f((unsigned int)(v0 & 0xffffu));
    a1 += b2f((unsigned int)((v0 >> 16) & 0xffffu));
    a2 += b2f((unsigned int)((v0 >> 32) & 0xffffu));
    a3 += b2f((unsigned int)((v0 >> 48) & 0xffffu));
    j += 2;
  }
  if (j < end && half == 0) {
    int c0 = col[j];
    unsigned long long v0 = xq[(size_t)c0 * 32 + l32];
    a0 += b2f((unsigned int)(v0 & 0xffffu));
    a1 += b2f((unsigned int)((v0 >> 16) & 0xffffu));
    a2 += b2f((unsigned int)((v0 >> 32) & 0xffffu));
    a3 += b2f((unsigned int)((v0 >> 48) & 0xffffu));
  }
  // combine the two halves
  a0 += __shfl_xor(a0, 32, 64);
  a1 += __shfl_xor(a1, 32, 64);
  a2 += __shfl_xor(a2, 32, 64);
  a3 += __shfl_xor(a3, 32, 64);
  if (half == 0) {
    unsigned long long r = (unsigned long long)f2b(a0) |
                           ((unsigned long long)f2b(a1) << 16) |
                           ((unsigned long long)f2b(a2) << 32) |
                           ((unsigned long long)f2b(a3) << 48);
    ((unsigned long long*)agg)[(size_t)wid * 32 + l32] = r;
  }
}

// ---- GEMM1: H = relu(A @ W1 + b1), [n,128]x[128,128], bf16 in/out ----
__global__ __launch_bounds__(256) void gemm1_kernel(
    const unsigned short* __restrict__ A, const unsigned short* __restrict__ W1T,
    const float* __restrict__ b1, unsigned short* __restrict__ H, int n) {
  const int wave = threadIdx.x >> 6;
  const int lane = threadIdx.x & 63;
  const int lr = lane & 15, lg = lane >> 4;
  const int rowBase = blockIdx.x * 64 + wave * 16;
  short8 a[4];
#pragma unroll
  for (int kt = 0; kt < 4; ++kt)
    a[kt] = *(const short8*)(A + (size_t)(rowBase + lr) * FEAT + kt * 32 + lg * 8);
  f32x4 acc[8];
#pragma unroll
  for (int ct = 0; ct < 8; ++ct) {
    const unsigned short* bp = W1T + (size_t)(ct * 16 + lr) * FEAT + lg * 8;
    f32x4 c = {0.f, 0.f, 0.f, 0.f};
    c = mfma16(a[0], *(const short8*)(bp), c);
    c = mfma16(a[1], *(const short8*)(bp + 32), c);
    c = mfma16(a[2], *(const short8*)(bp + 64), c);
    c = mfma16(a[3], *(const short8*)(bp + 96), c);
    acc[ct] = c;
  }
#pragma unroll
  for (int ct = 0; ct < 8; ++ct) {
    const int c = ct * 16 + lr;
    const float bias = b1[c];
#pragma unroll
    for (int j = 0; j < 4; ++j) {
      const int row = rowBase + lg * 4 + j;
      if (row < n) {
        float v = acc[ct][j] + bias;
        H[(size_t)row * FEAT + c] = f2b(v > 0.f ? v : 0.f);
      }
    }
  }
}

// ================= LDS-staged GEMM2 passes (round-8 structure) =================
// Block = 256 rows x 256 cols; 8 waves x 32 rows; the block's W2T slice (64 KB)
// + bias staged into LDS once, fragment-major -> conflict-free ds_read_b128.

// ---- statT: partial per-row online-softmax stats over a 256-col slice ----
__global__ __launch_bounds__(512) void statT_kernel(
    const unsigned short* __restrict__ H, const unsigned short* __restrict__ W2T,
    const float* __restrict__ b2, float* __restrict__ pm, float* __restrict__ ps,
    int nPad) {
  __shared__ short8 ldsB[4096];   // 64 KB
  __shared__ float ldsBias[256];
  const int wave = threadIdx.x >> 6;
  const int lane = threadIdx.x & 63;
  const int lr = lane & 15, lg = lane >> 4;
  const int nRowBlk = nPad >> 8;
  const int rowBlk = blockIdx.x % nRowBlk;
  const int colBlk = blockIdx.x / nRowBlk;
  const int rowBase = rowBlk * 256 + wave * 32;
  const int colBase = colBlk * 256;

#pragma unroll
  for (int r = 0; r < 8; ++r) {
    const int p = r * 8 + wave;
    const int ct = p >> 2, q = p & 3;
    ldsB[p * 64 + lane] =
        *(const short8*)(W2T + (size_t)(colBase + ct * 16 + lr) * FEAT + (q * 4 + lg) * 8);
  }
  if (threadIdx.x < 256) ldsBias[threadIdx.x] = b2[colBase + threadIdx.x];

  short8 a[2][4];
#pragma unroll
  for (int g = 0; g < 2; ++g)
#pragma unroll
    for (int kt = 0; kt < 4; ++kt)
      a[g][kt] = *(const short8*)(H + (size_t)(rowBase + g * 16 + lr) * FEAT + kt * 32 + lg * 8);
  __syncthreads();

  float m[2][4], s[2][4];
#pragma unroll
  for (int g = 0; g < 2; ++g)
#pragma unroll
    for (int j = 0; j < 4; ++j) { m[g][j] = -1e30f; s[g][j] = 0.f; }

#pragma unroll 4
  for (int ct = 0; ct < 16; ++ct) {
    short8 q0 = ldsB[(ct * 4 + 0) * 64 + lane];
    short8 q1 = ldsB[(ct * 4 + 1) * 64 + lane];
    short8 q2 = ldsB[(ct * 4 + 2) * 64 + lane];
    short8 q3 = ldsB[(ct * 4 + 3) * 64 + lane];
    f32x4 c0 = {0.f, 0.f, 0.f, 0.f};
    f32x4 c1 = {0.f, 0.f, 0.f, 0.f};
    c0 = mfma16(a[0][0], q0, c0);
    c1 = mfma16(a[1][0], q0, c1);
    c0 = mfma16(a[0][1], q1, c0);
    c1 = mfma16(a[1][1], q1, c1);
    c0 = mfma16(a[0][2], q2, c0);
    c1 = mfma16(a[1][2], q2, c1);
    c0 = mfma16(a[0][3], q3, c0);
    c1 = mfma16(a[1][3], q3, c1);
    const float bs = ldsBias[ct * 16 + lr];
    float e0[4], e1[4];
#pragma unroll
    for (int j = 0; j < 4; ++j) { e0[j] = c0[j] + bs; e1[j] = c1[j] + bs; }
    bool need = false;
#pragma unroll
    for (int j = 0; j < 4; ++j)
      need = need || (e0[j] > m[0][j] + 8.f) || (e1[j] > m[1][j] + 8.f);
    if (__any(need)) {
#pragma unroll
      for (int j = 0; j < 4; ++j) {
        float nm0 = fmaxf(m[0][j], e0[j]);
        s[0][j] = s[0][j] * __expf(m[0][j] - nm0) + __expf(e0[j] - nm0);
        m[0][j] = nm0;
        float nm1 = fmaxf(m[1][j], e1[j]);
        s[1][j] = s[1][j] * __expf(m[1][j] - nm1) + __expf(e1[j] - nm1);
        m[1][j] = nm1;
      }
    } else {
#pragma unroll
      for (int j = 0; j < 4; ++j) {
        s[0][j] += __expf(e0[j] - m[0][j]);
        s[1][j] += __expf(e1[j] - m[1][j]);
      }
    }
  }
#pragma unroll
  for (int g = 0; g < 2; ++g)
#pragma unroll
    for (int j = 0; j < 4; ++j) {
#pragma unroll
      for (int d = 1; d < 16; d <<= 1) {
        float om = __shfl_xor(m[g][j], d, 64);
        float os = __shfl_xor(s[g][j], d, 64);
        float nm = fmaxf(m[g][j], om);
        s[g][j] = s[g][j] * __expf(m[g][j] - nm) + os * __expf(om - nm);
        m[g][j] = nm;
      }
    }
  if (lr == 0) {
#pragma unroll
    for (int g = 0; g < 2; ++g)
#pragma unroll
      for (int j = 0; j < 4; ++j) {
        const int row = rowBase + g * 16 + lg * 4 + j;
        pm[(size_t)colBlk * nPad + row] = m[g][j];
        ps[(size_t)colBlk * nPad + row] = s[g][j];
      }
  }
}

// ---- mergeT: T[r] = M + ln(sum_k s_k * exp(m_k - M)) over the 8 col-slices ----
__global__ void mergeT_kernel(const float* __restrict__ pm, const float* __restrict__ ps,
                              float* __restrict__ T, int nPad) {
  int r = blockIdx.x * 256 + threadIdx.x;
  if (r < nPad) {
    float M = pm[r];
#pragma unroll
    for (int k = 1; k < 8; ++k) M = fmaxf(M, pm[(size_t)k * nPad + r]);
    float S = 0.f;
#pragma unroll
    for (int k = 0; k < 8; ++k) S += ps[(size_t)k * nPad + r] * __expf(pm[(size_t)k * nPad + r] - M);
    T[r] = M + __logf(S);
  }
}

// ---- fpacc: recompute logits, fp_partial[c] += sum_r exp(l[r,c] - T[r]) ----
__global__ __launch_bounds__(512) void fpacc_kernel(
    const unsigned short* __restrict__ H, const unsigned short* __restrict__ W2T,
    const float* __restrict__ b2, const float* __restrict__ T,
    float* __restrict__ partials, int n, int nPad) {
  __shared__ short8 ldsB[4096];   // 64 KB
  __shared__ float ldsBias[256];
  __shared__ float fp_w[8][256];  // 8 KB
  const int wave = threadIdx.x >> 6;
  const int lane = threadIdx.x & 63;
  const int lr = lane & 15, lg = lane >> 4;
  const int nRowBlk = nPad >> 8;
  const int rowBlk = blockIdx.x % nRowBlk;
  const int colBlk = blockIdx.x / nRowBlk;
  const int rowBase = rowBlk * 256 + wave * 32;
  const int colBase = colBlk * 256;

#pragma unroll
  for (int r = 0; r < 8; ++r) {
    const int p = r * 8 + wave;
    const int ct = p >> 2, q = p & 3;
    ldsB[p * 64 + lane] =
        *(const short8*)(W2T + (size_t)(colBase + ct * 16 + lr) * FEAT + (q * 4 + lg) * 8);
  }
  if (threadIdx.x < 256) ldsBias[threadIdx.x] = b2[colBase + threadIdx.x];

  short8 a[2][4];
#pragma unroll
  for (int g = 0; g < 2; ++g)
#pragma unroll
    for (int kt = 0; kt < 4; ++kt)
      a[g][kt] = *(const short8*)(H + (size_t)(rowBase + g * 16 + lr) * FEAT + kt * 32 + lg * 8);
  float Tj[2][4];
#pragma unroll
  for (int g = 0; g < 2; ++g)
#pragma unroll
    for (int j = 0; j < 4; ++j) {
      const int row = rowBase + g * 16 + lg * 4 + j;
      Tj[g][j] = (row < n) ? T[row] : 1e30f;  // pad rows contribute 0
    }
  __syncthreads();

#pragma unroll 4
  for (int ct = 0; ct < 16; ++ct) {
    short8 q0 = ldsB[(ct * 4 + 0) * 64 + lane];
    short8 q1 = ldsB[(ct * 4 + 1) * 64 + lane];
    short8 q2 = ldsB[(ct * 4 + 2) * 64 + lane];
    short8 q3 = ldsB[(ct * 4 + 3) * 64 + lane];
    f32x4 c0 = {0.f, 0.f, 0.f, 0.f};
    f32x4 c1 = {0.f, 0.f, 0.f, 0.f};
    c0 = mfma16(a[0][0], q0, c0);
    c1 = mfma16(a[1][0], q0, c1);
    c0 = mfma16(a[0][1], q1, c0);
    c1 = mfma16(a[1][1], q1, c1);
    c0 = mfma16(a[0][2], q2, c0);
    c1 = mfma16(a[1][2], q2, c1);
    c0 = mfma16(a[0][3], q3, c0);
    c1 = mfma16(a[1][3], q3, c1);
    const float bs = ldsBias[ct * 16 + lr];
    float p = __expf(c0[0] + bs - Tj[0][0]) + __expf(c0[1] + bs - Tj[0][1]) +
              __expf(c0[2] + bs - Tj[0][2]) + __expf(c0[3] + bs - Tj[0][3]) +
              __expf(c1[0] + bs - Tj[1][0]) + __expf(c1[1] + bs - Tj[1][1]) +
              __expf(c1[2] + bs - Tj[1][2]) + __expf(c1[3] + bs - Tj[1][3]);
    p += __shfl_xor(p, 16, 64);
    p += __shfl_xor(p, 32, 64);
    if (lg == 0) fp_w[wave][ct * 16 + lr] = p;
  }
  __syncthreads();
  if (threadIdx.x < 256) {
    float sum = 0.f;
#pragma unroll
    for (int w = 0; w < 8; ++w) sum += fp_w[w][threadIdx.x];
    partials[(size_t)rowBlk * FPL + colBase + threadIdx.x] += sum;
  }
}

__global__ void reduce_kernel(const float* __restrict__ partials, float* __restrict__ out, int nPart) {
  int c = blockIdx.x * 256 + threadIdx.x;
  if (c < FPL) {
    float s = 0.f;
    for (int p = 0; p < nPart; ++p) s += partials[(size_t)p * FPL + c];
    out[c] = s;
  }
}

extern "C" void kernel_launch(void* const* d_in, const int* in_sizes, int n_in,
                              void* d_out, int out_size, void* d_ws, size_t ws_size,
                              hipStream_t stream) {
  const float* atoms = (const float*)d_in[0];
  const float* W1 = (const float*)d_in[1];
  const float* b1 = (const float*)d_in[2];
  const float* W2 = (const float*)d_in[3];
  const float* b2 = (const float*)d_in[4];
  const int* esrc = (const int*)d_in[5];
  const int* edst = (const int*)d_in[6];
  const int nAtoms = in_sizes[0] / FEAT;
  const int nEdges = in_sizes[5];
  if (nAtoms <= 0) return;

  const int g2Blocks = (nAtoms + 255) / 256;  // 256-row tiles for statT/fpacc
  const int nPad = g2Blocks * 256;
  const int g1Blocks = nPad / 64;
  const int nChunks = (nAtoms + 1023) / 1024;
  const int nBuckets = (nAtoms + 63) / 64;

  size_t off = 0;
  auto alloc = [&](size_t bytes) -> void* {
    void* p = (char*)d_ws + off;
    off += (bytes + 255) & ~(size_t)255;
    return p;
  };
  unsigned short* P = (unsigned short*)alloc((size_t)nPad * FEAT * 2);
  unsigned short* Q = (unsigned short*)alloc((size_t)nPad * FEAT * 2);
  unsigned short* W1T = (unsigned short*)alloc((size_t)FEAT * FEAT * 2);
  unsigned short* W2T = (unsigned short*)alloc((size_t)FEAT * FPL * 2);
  int* counts = (int*)alloc((size_t)nAtoms * 4);
  int* cursor = (int*)alloc((size_t)nAtoms * 4);
  int* rp = (int*)alloc(((size_t)nAtoms + 1) * 4);
  int* ex = (int*)alloc((size_t)nAtoms * 4);
  int* chunkSum = (int*)alloc((size_t)nChunks * 4);
  int* chunkOff = (int*)alloc((size_t)nChunks * 4);
  int* bcur = (int*)alloc((size_t)nBuckets * 4);
  int* col = (int*)alloc((size_t)nEdges * 4);
  int2* pairTmp = (int2*)alloc((size_t)nEdges * 8);
  float* pm = (float*)alloc((size_t)8 * nPad * 4);
  float* ps = (float*)alloc((size_t)8 * nPad * 4);
  float* Trow = (float*)alloc((size_t)nPad * 4);
  float* partials = (float*)alloc((size_t)g2Blocks * FPL * 4);

  hipMemsetAsync(counts, 0, (size_t)nAtoms * 4, stream);
  hipMemsetAsync(partials, 0, (size_t)g2Blocks * FPL * 4, stream);
  hipMemsetAsync(P + (size_t)nAtoms * FEAT, 0, (size_t)(nPad - nAtoms) * FEAT * 2, stream);
  hipMemsetAsync(Q + (size_t)nAtoms * FEAT, 0, (size_t)(nPad - nAtoms) * FEAT * 2, stream);

  const int n2 = in_sizes[0] / 2;
  cvt_kernel<<<(n2 + 255) / 256, 256, 0, stream>>>(atoms, P, n2);
  cvtT_kernel<<<(FEAT * FEAT + 255) / 256, 256, 0, stream>>>(W1, W1T, FEAT, FEAT);
  cvtT_kernel<<<(FEAT * FPL + 255) / 256, 256, 0, stream>>>(W2, W2T, FEAT, FPL);
  count_kernel<<<(nEdges + 255) / 256, 256, 0, stream>>>(edst, counts, nEdges);
  scan1_kernel<<<nChunks, 1024, 0, stream>>>(counts, ex, chunkSum, nAtoms);
  scan2_kernel<<<1, 1024, 0, stream>>>(chunkSum, chunkOff, nChunks);
  scan3_kernel<<<(nAtoms + 255) / 256, 256, 0, stream>>>(ex, chunkOff, chunkSum, rp, nAtoms, nChunks);
  copy_kernel<<<(nAtoms + 255) / 256, 256, 0, stream>>>(rp, cursor, nAtoms);
  initb_kernel<<<(nBuckets + 255) / 256, 256, 0, stream>>>(rp, bcur, nBuckets);
  binA_kernel<<<(nEdges + 255) / 256, 256, 0, stream>>>(esrc, edst, bcur, pairTmp, nEdges);
  binB_kernel<<<(nEdges + 255) / 256, 256, 0, stream>>>(pairTmp, cursor, col, nEdges);

  unsigned short* x = P;
  unsigned short* y = Q;
  for (int step = 0; step < 3; ++step) {
    gather_kernel<<<(nAtoms + 3) / 4, 256, 0, stream>>>(x, rp, col, y, nAtoms);
    gemm1_kernel<<<g1Blocks, 256, 0, stream>>>(y, W1T, b1, y, nAtoms);
    statT_kernel<<<g2Blocks * 8, 512, 0, stream>>>(y, W2T, b2, pm, ps, nPad);
    mergeT_kernel<<<(nPad + 255) / 256, 256, 0, stream>>>(pm, ps, Trow, nPad);
    fpacc_kernel<<<g2Blocks * 8, 512, 0, stream>>>(y, W2T, b2, Trow, partials, nAtoms, nPad);
    unsigned short* t = x; x = y; y = t;
  }
  reduce_kernel<<<(FPL + 255) / 256, 256, 0, stream>>>(partials, (float*)d_out, g2Blocks);
}

// Round 10
// 788.532 us; speedup vs baseline: 1.4630x; 1.4630x over previous
//
#include <hip/hip_runtime.h>

typedef short short8 __attribute__((ext_vector_type(8)));
typedef __bf16 bf16x8 __attribute__((ext_vector_type(8)));
typedef float f32x4 __attribute__((ext_vector_type(4)));

#define FEAT 128
#define FPL 2048

__device__ __forceinline__ float b2f(unsigned int u) {
  union { unsigned int u; float f; } c; c.u = u << 16; return c.f;
}
__device__ __forceinline__ unsigned short f2b(float f) {
  union { float f; unsigned int u; } c; c.f = f;
  unsigned int r = c.u + 0x7fffu + ((c.u >> 16) & 1u);
  return (unsigned short)(r >> 16);
}
__device__ __forceinline__ f32x4 mfma16(short8 a, short8 b, f32x4 c) {
  return __builtin_amdgcn_mfma_f32_16x16x32_bf16(
      __builtin_bit_cast(bf16x8, a), __builtin_bit_cast(bf16x8, b), c, 0, 0, 0);
}

// ---- conversion kernels ----
__global__ void cvt_kernel(const float* __restrict__ in, unsigned short* __restrict__ out, int n2) {
  int i = blockIdx.x * 256 + threadIdx.x;
  if (i < n2) {
    float2 v = ((const float2*)in)[i];
    unsigned int lo = f2b(v.x), hi = f2b(v.y);
    ((unsigned int*)out)[i] = lo | (hi << 16);
  }
}

// W[K][N] (row-major) -> WT[N][K] bf16
__global__ void cvtT_kernel(const float* __restrict__ W, unsigned short* __restrict__ WT, int K, int N) {
  int i = blockIdx.x * 256 + threadIdx.x;
  if (i < K * N) {
    int k = i / N, c = i - k * N;
    WT[(size_t)c * K + k] = f2b(W[i]);
  }
}

// ---- CSR build ----
__global__ void count_kernel(const int* __restrict__ dst, int* __restrict__ cnt, int n) {
  int i = blockIdx.x * 256 + threadIdx.x;
  if (i < n) atomicAdd(&cnt[dst[i]], 1);
}

// hierarchical exclusive scan: scan1 (per-1024 chunk) -> scan2 (chunk sums) -> scan3 (add offsets)
__global__ __launch_bounds__(1024) void scan1_kernel(const int* __restrict__ cnt,
    int* __restrict__ ex, int* __restrict__ chunkSum, int n) {
  __shared__ int sd[1024];
  const int i = blockIdx.x * 1024 + threadIdx.x;
  int v = (i < n) ? cnt[i] : 0;
  sd[threadIdx.x] = v;
  __syncthreads();
  int sum = v;
  for (int off = 1; off < 1024; off <<= 1) {
    int t = (threadIdx.x >= (unsigned)off) ? sd[threadIdx.x - off] : 0;
    __syncthreads();
    sum += t;
    sd[threadIdx.x] = sum;
    __syncthreads();
  }
  if (i < n) ex[i] = sum - v;
  if (threadIdx.x == 1023) chunkSum[blockIdx.x] = sum;
}

__global__ __launch_bounds__(1024) void scan2_kernel(const int* __restrict__ chunkSum,
    int* __restrict__ chunkOff, int nChunks) {
  __shared__ int sd[1024];
  int v = (threadIdx.x < (unsigned)nChunks) ? chunkSum[threadIdx.x] : 0;
  sd[threadIdx.x] = v;
  __syncthreads();
  int sum = v;
  for (int off = 1; off < 1024; off <<= 1) {
    int t = (threadIdx.x >= (unsigned)off) ? sd[threadIdx.x - off] : 0;
    __syncthreads();
    sum += t;
    sd[threadIdx.x] = sum;
    __syncthreads();
  }
  if (threadIdx.x < (unsigned)nChunks) chunkOff[threadIdx.x] = sum - v;
}

__global__ void scan3_kernel(const int* __restrict__ ex, const int* __restrict__ chunkOff,
    const int* __restrict__ chunkSum, int* __restrict__ rp, int n, int nChunks) {
  int i = blockIdx.x * 256 + threadIdx.x;
  if (i < n) rp[i] = ex[i] + chunkOff[i >> 10];
  if (i == 0) rp[n] = chunkOff[nChunks - 1] + chunkSum[nChunks - 1];
}

__global__ void copy_kernel(const int* __restrict__ a, int* __restrict__ b, int n) {
  int i = blockIdx.x * 256 + threadIdx.x;
  if (i < n) b[i] = a[i];
}

// XCD-partitioned CSR fill. Round-8 direct fill wrote 100 MB HBM: 4-B random
// stores across a 6.4 MB col array from all 8 XCDs -> every 64-B line dirtied
// in multiple XCD L2s -> repeated write-backs (16x amplification). Round-9's
// 782-bucket binning was worse (contended atomics, 376 us). Here blocks with
// blockIdx%8==p handle only edges whose dst is in contiguous slice p, so each
// XCD's L2 exclusively owns a disjoint col/cursor region: write-backs ~6.4 MB
// once. Cost: 8x re-stream of the L3-resident edge list (~10 us). The %8->XCD
// mapping is a performance guess only -- correctness never depends on it.
__global__ __launch_bounds__(256) void fillx_kernel(const int* __restrict__ src,
    const int* __restrict__ dst, int* __restrict__ cursor, int* __restrict__ col,
    int n, int nAtoms) {
  const int part = blockIdx.x & 7;
  const int blkInPart = blockIdx.x >> 3;
  const int nBlkPerPart = gridDim.x >> 3;
  const int partSize = (nAtoms + 7) >> 3;
  const int lo = part * partSize;
  const int hi = min(lo + partSize, nAtoms);
  const int stride = nBlkPerPart * 256;
  for (int i = blkInPart * 256 + (int)threadIdx.x; i < n; i += stride) {
    int d = dst[i];
    if (d >= lo && d < hi) {
      int p = atomicAdd(&cursor[d], 1);
      col[p] = src[i];
    }
  }
}

// ---- neighbor gather: agg[i] = x[i] + sum_{j in N(i)} x[j], bf16 in/out, fp32 accum ----
// One wave per atom; lane halves (32+32) process 2 edges per iteration with 8B
// loads (dwordx2), combined at the end via shfl_xor(32).
__global__ __launch_bounds__(256) void gather_kernel(const unsigned short* __restrict__ x,
    const int* __restrict__ rp, const int* __restrict__ col,
    unsigned short* __restrict__ agg, int n) {
  int wid = (blockIdx.x * 256 + threadIdx.x) >> 6;
  int lane = threadIdx.x & 63;
  if (wid >= n) return;
  const int half = lane >> 5;
  const int l32 = lane & 31;
  const unsigned long long* xq = (const unsigned long long*)x;  // 8B = 4 bf16

  float a0, a1, a2, a3;
  {
    unsigned long long sv = xq[(size_t)wid * 32 + l32];
    if (half == 0) {
      a0 = b2f((unsigned int)(sv & 0xffffu));
      a1 = b2f((unsigned int)((sv >> 16) & 0xffffu));
      a2 = b2f((unsigned int)((sv >> 32) & 0xffffu));
      a3 = b2f((unsigned int)((sv >> 48) & 0xffffu));
    } else {
      a0 = a1 = a2 = a3 = 0.f;
    }
  }
  const int beg = rp[wid], end = rp[wid + 1];
  int j = beg;
  for (; j + 4 <= end; j += 4) {
    int c0 = col[j + half];
    int c1 = col[j + 2 + half];
    unsigned long long v0 = xq[(size_t)c0 * 32 + l32];
    unsigned long long v1 = xq[(size_t)c1 * 32 + l32];
    a0 += b2f((unsigned int)(v0 & 0xffffu)) + b2f((unsigned int)(v1 & 0xffffu));
    a1 += b2f((unsigned int)((v0 >> 16) & 0xffffu)) + b2f((unsigned int)((v1 >> 16) & 0xffffu));
    a2 += b2f((unsigned int)((v0 >> 32) & 0xffffu)) + b2f((unsigned int)((v1 >> 32) & 0xffffu));
    a3 += b2f((unsigned int)((v0 >> 48) & 0xffffu)) + b2f((unsigned int)((v1 >> 48) & 0xffffu));
  }
  if (j + 2 <= end) {
    int c0 = col[j + half];
    unsigned long long v0 = xq[(size_t)c0 * 32 + l32];
    a0 += b2f((unsigned int)(v0 & 0xffffu));
    a1 += b2f((unsigned int)((v0 >> 16) & 0xffffu));
    a2 += b2f((unsigned int)((v0 >> 32) & 0xffffu));
    a3 += b2f((unsigned int)((v0 >> 48) & 0xffffu));
    j += 2;
  }
  if (j < end && half == 0) {
    int c0 = col[j];
    unsigned long long v0 = xq[(size_t)c0 * 32 + l32];
    a0 += b2f((unsigned int)(v0 & 0xffffu));
    a1 += b2f((unsigned int)((v0 >> 16) & 0xffffu));
    a2 += b2f((unsigned int)((v0 >> 32) & 0xffffu));
    a3 += b2f((unsigned int)((v0 >> 48) & 0xffffu));
  }
  // combine the two halves
  a0 += __shfl_xor(a0, 32, 64);
  a1 += __shfl_xor(a1, 32, 64);
  a2 += __shfl_xor(a2, 32, 64);
  a3 += __shfl_xor(a3, 32, 64);
  if (half == 0) {
    unsigned long long r = (unsigned long long)f2b(a0) |
                           ((unsigned long long)f2b(a1) << 16) |
                           ((unsigned long long)f2b(a2) << 32) |
                           ((unsigned long long)f2b(a3) << 48);
    ((unsigned long long*)agg)[(size_t)wid * 32 + l32] = r;
  }
}

// ---- GEMM1: H = relu(A @ W1 + b1), [n,128]x[128,128], bf16 in/out ----
__global__ __launch_bounds__(256) void gemm1_kernel(
    const unsigned short* __restrict__ A, const unsigned short* __restrict__ W1T,
    const float* __restrict__ b1, unsigned short* __restrict__ H, int n) {
  const int wave = threadIdx.x >> 6;
  const int lane = threadIdx.x & 63;
  const int lr = lane & 15, lg = lane >> 4;
  const int rowBase = blockIdx.x * 64 + wave * 16;
  short8 a[4];
#pragma unroll
  for (int kt = 0; kt < 4; ++kt)
    a[kt] = *(const short8*)(A + (size_t)(rowBase + lr) * FEAT + kt * 32 + lg * 8);
  f32x4 acc[8];
#pragma unroll
  for (int ct = 0; ct < 8; ++ct) {
    const unsigned short* bp = W1T + (size_t)(ct * 16 + lr) * FEAT + lg * 8;
    f32x4 c = {0.f, 0.f, 0.f, 0.f};
    c = mfma16(a[0], *(const short8*)(bp), c);
    c = mfma16(a[1], *(const short8*)(bp + 32), c);
    c = mfma16(a[2], *(const short8*)(bp + 64), c);
    c = mfma16(a[3], *(const short8*)(bp + 96), c);
    acc[ct] = c;
  }
#pragma unroll
  for (int ct = 0; ct < 8; ++ct) {
    const int c = ct * 16 + lr;
    const float bias = b1[c];
#pragma unroll
    for (int j = 0; j < 4; ++j) {
      const int row = rowBase + lg * 4 + j;
      if (row < n) {
        float v = acc[ct][j] + bias;
        H[(size_t)row * FEAT + c] = f2b(v > 0.f ? v : 0.f);
      }
    }
  }
}

// ================= LDS-staged GEMM2 passes (round-8 structure) =================
// Block = 256 rows x 256 cols; 8 waves x 32 rows; the block's W2T slice (64 KB)
// + bias staged into LDS once, fragment-major -> conflict-free ds_read_b128.

// ---- statT: partial per-row online-softmax stats over a 256-col slice ----
__global__ __launch_bounds__(512) void statT_kernel(
    const unsigned short* __restrict__ H, const unsigned short* __restrict__ W2T,
    const float* __restrict__ b2, float* __restrict__ pm, float* __restrict__ ps,
    int nPad) {
  __shared__ short8 ldsB[4096];   // 64 KB
  __shared__ float ldsBias[256];
  const int wave = threadIdx.x >> 6;
  const int lane = threadIdx.x & 63;
  const int lr = lane & 15, lg = lane >> 4;
  const int nRowBlk = nPad >> 8;
  const int rowBlk = blockIdx.x % nRowBlk;
  const int colBlk = blockIdx.x / nRowBlk;
  const int rowBase = rowBlk * 256 + wave * 32;
  const int colBase = colBlk * 256;

#pragma unroll
  for (int r = 0; r < 8; ++r) {
    const int p = r * 8 + wave;
    const int ct = p >> 2, q = p & 3;
    ldsB[p * 64 + lane] =
        *(const short8*)(W2T + (size_t)(colBase + ct * 16 + lr) * FEAT + (q * 4 + lg) * 8);
  }
  if (threadIdx.x < 256) ldsBias[threadIdx.x] = b2[colBase + threadIdx.x];

  short8 a[2][4];
#pragma unroll
  for (int g = 0; g < 2; ++g)
#pragma unroll
    for (int kt = 0; kt < 4; ++kt)
      a[g][kt] = *(const short8*)(H + (size_t)(rowBase + g * 16 + lr) * FEAT + kt * 32 + lg * 8);
  __syncthreads();

  float m[2][4], s[2][4];
#pragma unroll
  for (int g = 0; g < 2; ++g)
#pragma unroll
    for (int j = 0; j < 4; ++j) { m[g][j] = -1e30f; s[g][j] = 0.f; }

#pragma unroll 4
  for (int ct = 0; ct < 16; ++ct) {
    short8 q0 = ldsB[(ct * 4 + 0) * 64 + lane];
    short8 q1 = ldsB[(ct * 4 + 1) * 64 + lane];
    short8 q2 = ldsB[(ct * 4 + 2) * 64 + lane];
    short8 q3 = ldsB[(ct * 4 + 3) * 64 + lane];
    f32x4 c0 = {0.f, 0.f, 0.f, 0.f};
    f32x4 c1 = {0.f, 0.f, 0.f, 0.f};
    c0 = mfma16(a[0][0], q0, c0);
    c1 = mfma16(a[1][0], q0, c1);
    c0 = mfma16(a[0][1], q1, c0);
    c1 = mfma16(a[1][1], q1, c1);
    c0 = mfma16(a[0][2], q2, c0);
    c1 = mfma16(a[1][2], q2, c1);
    c0 = mfma16(a[0][3], q3, c0);
    c1 = mfma16(a[1][3], q3, c1);
    const float bs = ldsBias[ct * 16 + lr];
    float e0[4], e1[4];
#pragma unroll
    for (int j = 0; j < 4; ++j) { e0[j] = c0[j] + bs; e1[j] = c1[j] + bs; }
    bool need = false;
#pragma unroll
    for (int j = 0; j < 4; ++j)
      need = need || (e0[j] > m[0][j] + 8.f) || (e1[j] > m[1][j] + 8.f);
    if (__any(need)) {
#pragma unroll
      for (int j = 0; j < 4; ++j) {
        float nm0 = fmaxf(m[0][j], e0[j]);
        s[0][j] = s[0][j] * __expf(m[0][j] - nm0) + __expf(e0[j] - nm0);
        m[0][j] = nm0;
        float nm1 = fmaxf(m[1][j], e1[j]);
        s[1][j] = s[1][j] * __expf(m[1][j] - nm1) + __expf(e1[j] - nm1);
        m[1][j] = nm1;
      }
    } else {
#pragma unroll
      for (int j = 0; j < 4; ++j) {
        s[0][j] += __expf(e0[j] - m[0][j]);
        s[1][j] += __expf(e1[j] - m[1][j]);
      }
    }
  }
#pragma unroll
  for (int g = 0; g < 2; ++g)
#pragma unroll
    for (int j = 0; j < 4; ++j) {
#pragma unroll
      for (int d = 1; d < 16; d <<= 1) {
        float om = __shfl_xor(m[g][j], d, 64);
        float os = __shfl_xor(s[g][j], d, 64);
        float nm = fmaxf(m[g][j], om);
        s[g][j] = s[g][j] * __expf(m[g][j] - nm) + os * __expf(om - nm);
        m[g][j] = nm;
      }
    }
  if (lr == 0) {
#pragma unroll
    for (int g = 0; g < 2; ++g)
#pragma unroll
      for (int j = 0; j < 4; ++j) {
        const int row = rowBase + g * 16 + lg * 4 + j;
        pm[(size_t)colBlk * nPad + row] = m[g][j];
        ps[(size_t)colBlk * nPad + row] = s[g][j];
      }
  }
}

// ---- mergeT: T[r] = M + ln(sum_k s_k * exp(m_k - M)) over the 8 col-slices ----
__global__ void mergeT_kernel(const float* __restrict__ pm, const float* __restrict__ ps,
                              float* __restrict__ T, int nPad) {
  int r = blockIdx.x * 256 + threadIdx.x;
  if (r < nPad) {
    float M = pm[r];
#pragma unroll
    for (int k = 1; k < 8; ++k) M = fmaxf(M, pm[(size_t)k * nPad + r]);
    float S = 0.f;
#pragma unroll
    for (int k = 0; k < 8; ++k) S += ps[(size_t)k * nPad + r] * __expf(pm[(size_t)k * nPad + r] - M);
    T[r] = M + __logf(S);
  }
}

// ---- fpacc: recompute logits, fp_partial[c] += sum_r exp(l[r,c] - T[r]) ----
__global__ __launch_bounds__(512) void fpacc_kernel(
    const unsigned short* __restrict__ H, const unsigned short* __restrict__ W2T,
    const float* __restrict__ b2, const float* __restrict__ T,
    float* __restrict__ partials, int n, int nPad) {
  __shared__ short8 ldsB[4096];   // 64 KB
  __shared__ float ldsBias[256];
  __shared__ float fp_w[8][256];  // 8 KB
  const int wave = threadIdx.x >> 6;
  const int lane = threadIdx.x & 63;
  const int lr = lane & 15, lg = lane >> 4;
  const int nRowBlk = nPad >> 8;
  const int rowBlk = blockIdx.x % nRowBlk;
  const int colBlk = blockIdx.x / nRowBlk;
  const int rowBase = rowBlk * 256 + wave * 32;
  const int colBase = colBlk * 256;

#pragma unroll
  for (int r = 0; r < 8; ++r) {
    const int p = r * 8 + wave;
    const int ct = p >> 2, q = p & 3;
    ldsB[p * 64 + lane] =
        *(const short8*)(W2T + (size_t)(colBase + ct * 16 + lr) * FEAT + (q * 4 + lg) * 8);
  }
  if (threadIdx.x < 256) ldsBias[threadIdx.x] = b2[colBase + threadIdx.x];

  short8 a[2][4];
#pragma unroll
  for (int g = 0; g < 2; ++g)
#pragma unroll
    for (int kt = 0; kt < 4; ++kt)
      a[g][kt] = *(const short8*)(H + (size_t)(rowBase + g * 16 + lr) * FEAT + kt * 32 + lg * 8);
  float Tj[2][4];
#pragma unroll
  for (int g = 0; g < 2; ++g)
#pragma unroll
    for (int j = 0; j < 4; ++j) {
      const int row = rowBase + g * 16 + lg * 4 + j;
      Tj[g][j] = (row < n) ? T[row] : 1e30f;  // pad rows contribute 0
    }
  __syncthreads();

#pragma unroll 4
  for (int ct = 0; ct < 16; ++ct) {
    short8 q0 = ldsB[(ct * 4 + 0) * 64 + lane];
    short8 q1 = ldsB[(ct * 4 + 1) * 64 + lane];
    short8 q2 = ldsB[(ct * 4 + 2) * 64 + lane];
    short8 q3 = ldsB[(ct * 4 + 3) * 64 + lane];
    f32x4 c0 = {0.f, 0.f, 0.f, 0.f};
    f32x4 c1 = {0.f, 0.f, 0.f, 0.f};
    c0 = mfma16(a[0][0], q0, c0);
    c1 = mfma16(a[1][0], q0, c1);
    c0 = mfma16(a[0][1], q1, c0);
    c1 = mfma16(a[1][1], q1, c1);
    c0 = mfma16(a[0][2], q2, c0);
    c1 = mfma16(a[1][2], q2, c1);
    c0 = mfma16(a[0][3], q3, c0);
    c1 = mfma16(a[1][3], q3, c1);
    const float bs = ldsBias[ct * 16 + lr];
    float p = __expf(c0[0] + bs - Tj[0][0]) + __expf(c0[1] + bs - Tj[0][1]) +
              __expf(c0[2] + bs - Tj[0][2]) + __expf(c0[3] + bs - Tj[0][3]) +
              __expf(c1[0] + bs - Tj[1][0]) + __expf(c1[1] + bs - Tj[1][1]) +
              __expf(c1[2] + bs - Tj[1][2]) + __expf(c1[3] + bs - Tj[1][3]);
    p += __shfl_xor(p, 16, 64);
    p += __shfl_xor(p, 32, 64);
    if (lg == 0) fp_w[wave][ct * 16 + lr] = p;
  }
  __syncthreads();
  if (threadIdx.x < 256) {
    float sum = 0.f;
#pragma unroll
    for (int w = 0; w < 8; ++w) sum += fp_w[w][threadIdx.x];
    partials[(size_t)rowBlk * FPL + colBase + threadIdx.x] += sum;
  }
}

__global__ void reduce_kernel(const float* __restrict__ partials, float* __restrict__ out, int nPart) {
  int c = blockIdx.x * 256 + threadIdx.x;
  if (c < FPL) {
    float s = 0.f;
    for (int p = 0; p < nPart; ++p) s += partials[(size_t)p * FPL + c];
    out[c] = s;
  }
}

extern "C" void kernel_launch(void* const* d_in, const int* in_sizes, int n_in,
                              void* d_out, int out_size, void* d_ws, size_t ws_size,
                              hipStream_t stream) {
  const float* atoms = (const float*)d_in[0];
  const float* W1 = (const float*)d_in[1];
  const float* b1 = (const float*)d_in[2];
  const float* W2 = (const float*)d_in[3];
  const float* b2 = (const float*)d_in[4];
  const int* esrc = (const int*)d_in[5];
  const int* edst = (const int*)d_in[6];
  const int nAtoms = in_sizes[0] / FEAT;
  const int nEdges = in_sizes[5];
  if (nAtoms <= 0) return;

  const int g2Blocks = (nAtoms + 255) / 256;  // 256-row tiles for statT/fpacc
  const int nPad = g2Blocks * 256;
  const int g1Blocks = nPad / 64;
  const int nChunks = (nAtoms + 1023) / 1024;

  size_t off = 0;
  auto alloc = [&](size_t bytes) -> void* {
    void* p = (char*)d_ws + off;
    off += (bytes + 255) & ~(size_t)255;
    return p;
  };
  unsigned short* P = (unsigned short*)alloc((size_t)nPad * FEAT * 2);
  unsigned short* Q = (unsigned short*)alloc((size_t)nPad * FEAT * 2);
  unsigned short* W1T = (unsigned short*)alloc((size_t)FEAT * FEAT * 2);
  unsigned short* W2T = (unsigned short*)alloc((size_t)FEAT * FPL * 2);
  int* counts = (int*)alloc((size_t)nAtoms * 4);
  int* cursor = (int*)alloc((size_t)nAtoms * 4);
  int* rp = (int*)alloc(((size_t)nAtoms + 1) * 4);
  int* ex = (int*)alloc((size_t)nAtoms * 4);
  int* chunkSum = (int*)alloc((size_t)nChunks * 4);
  int* chunkOff = (int*)alloc((size_t)nChunks * 4);
  int* col = (int*)alloc((size_t)nEdges * 4);
  float* pm = (float*)alloc((size_t)8 * nPad * 4);
  float* ps = (float*)alloc((size_t)8 * nPad * 4);
  float* Trow = (float*)alloc((size_t)nPad * 4);
  float* partials = (float*)alloc((size_t)g2Blocks * FPL * 4);

  hipMemsetAsync(counts, 0, (size_t)nAtoms * 4, stream);
  hipMemsetAsync(partials, 0, (size_t)g2Blocks * FPL * 4, stream);
  hipMemsetAsync(P + (size_t)nAtoms * FEAT, 0, (size_t)(nPad - nAtoms) * FEAT * 2, stream);
  hipMemsetAsync(Q + (size_t)nAtoms * FEAT, 0, (size_t)(nPad - nAtoms) * FEAT * 2, stream);

  const int n2 = in_sizes[0] / 2;
  cvt_kernel<<<(n2 + 255) / 256, 256, 0, stream>>>(atoms, P, n2);
  cvtT_kernel<<<(FEAT * FEAT + 255) / 256, 256, 0, stream>>>(W1, W1T, FEAT, FEAT);
  cvtT_kernel<<<(FEAT * FPL + 255) / 256, 256, 0, stream>>>(W2, W2T, FEAT, FPL);
  count_kernel<<<(nEdges + 255) / 256, 256, 0, stream>>>(edst, counts, nEdges);
  scan1_kernel<<<nChunks, 1024, 0, stream>>>(counts, ex, chunkSum, nAtoms);
  scan2_kernel<<<1, 1024, 0, stream>>>(chunkSum, chunkOff, nChunks);
  scan3_kernel<<<(nAtoms + 255) / 256, 256, 0, stream>>>(ex, chunkOff, chunkSum, rp, nAtoms, nChunks);
  copy_kernel<<<(nAtoms + 255) / 256, 256, 0, stream>>>(rp, cursor, nAtoms);
  fillx_kernel<<<1024, 256, 0, stream>>>(esrc, edst, cursor, col, nEdges, nAtoms);

  unsigned short* x = P;
  unsigned short* y = Q;
  for (int step = 0; step < 3; ++step) {
    gather_kernel<<<(nAtoms + 3) / 4, 256, 0, stream>>>(x, rp, col, y, nAtoms);
    gemm1_kernel<<<g1Blocks, 256, 0, stream>>>(y, W1T, b1, y, nAtoms);
    statT_kernel<<<g2Blocks * 8, 512, 0, stream>>>(y, W2T, b2, pm, ps, nPad);
    mergeT_kernel<<<(nPad + 255) / 256, 256, 0, stream>>>(pm, ps, Trow, nPad);
    fpacc_kernel<<<g2Blocks * 8, 512, 0, stream>>>(y, W2T, b2, Trow, partials, nAtoms, nPad);
    unsigned short* t = x; x = y; y = t;
  }
  reduce_kernel<<<(FPL + 255) / 256, 256, 0, stream>>>(partials, (float*)d_out, g2Blocks);
}

// Round 11
// 780.748 us; speedup vs baseline: 1.4776x; 1.0100x over previous
//
#include <hip/hip_runtime.h>

typedef short short8 __attribute__((ext_vector_type(8)));
typedef __bf16 bf16x8 __attribute__((ext_vector_type(8)));
typedef float f32x4 __attribute__((ext_vector_type(4)));

#define FEAT 128
#define FPL 2048
#define LOG2E 1.4426950408889634f

__device__ __forceinline__ float b2f(unsigned int u) {
  union { unsigned int u; float f; } c; c.u = u << 16; return c.f;
}
__device__ __forceinline__ unsigned short f2b(float f) {
  union { float f; unsigned int u; } c; c.f = f;
  unsigned int r = c.u + 0x7fffu + ((c.u >> 16) & 1u);
  return (unsigned short)(r >> 16);
}
__device__ __forceinline__ f32x4 mfma16(short8 a, short8 b, f32x4 c) {
  return __builtin_amdgcn_mfma_f32_16x16x32_bf16(
      __builtin_bit_cast(bf16x8, a), __builtin_bit_cast(bf16x8, b), c, 0, 0, 0);
}
// 2^x in one instruction. gfx9-lineage VALU is fully interlocked (trans->VALU
// RAW needs no manual nops), so bare inline asm is safe here.
__device__ __forceinline__ float exp2x(float x) {
  float r; asm("v_exp_f32 %0, %1" : "=v"(r) : "v"(x)); return r;
}

// ---- conversion kernels ----
__global__ void cvt_kernel(const float* __restrict__ in, unsigned short* __restrict__ out, int n2) {
  int i = blockIdx.x * 256 + threadIdx.x;
  if (i < n2) {
    float2 v = ((const float2*)in)[i];
    unsigned int lo = f2b(v.x), hi = f2b(v.y);
    ((unsigned int*)out)[i] = lo | (hi << 16);
  }
}

// W[K][N] (row-major) -> WT[N][K] bf16, optionally pre-scaled (log2e for W2 so
// the softmax runs in exp2 domain -- deletes the mul inside every __expf).
__global__ void cvtT_kernel(const float* __restrict__ W, unsigned short* __restrict__ WT,
                            int K, int N, float scale) {
  int i = blockIdx.x * 256 + threadIdx.x;
  if (i < K * N) {
    int k = i / N, c = i - k * N;
    WT[(size_t)c * K + k] = f2b(W[i] * scale);
  }
}

// ---- CSR build ----
__global__ void count_kernel(const int* __restrict__ dst, int* __restrict__ cnt, int n) {
  int i = blockIdx.x * 256 + threadIdx.x;
  if (i < n) atomicAdd(&cnt[dst[i]], 1);
}

// hierarchical exclusive scan
__global__ __launch_bounds__(1024) void scan1_kernel(const int* __restrict__ cnt,
    int* __restrict__ ex, int* __restrict__ chunkSum, int n) {
  __shared__ int sd[1024];
  const int i = blockIdx.x * 1024 + threadIdx.x;
  int v = (i < n) ? cnt[i] : 0;
  sd[threadIdx.x] = v;
  __syncthreads();
  int sum = v;
  for (int off = 1; off < 1024; off <<= 1) {
    int t = (threadIdx.x >= (unsigned)off) ? sd[threadIdx.x - off] : 0;
    __syncthreads();
    sum += t;
    sd[threadIdx.x] = sum;
    __syncthreads();
  }
  if (i < n) ex[i] = sum - v;
  if (threadIdx.x == 1023) chunkSum[blockIdx.x] = sum;
}

__global__ __launch_bounds__(1024) void scan2_kernel(const int* __restrict__ chunkSum,
    int* __restrict__ chunkOff, int nChunks) {
  __shared__ int sd[1024];
  int v = (threadIdx.x < (unsigned)nChunks) ? chunkSum[threadIdx.x] : 0;
  sd[threadIdx.x] = v;
  __syncthreads();
  int sum = v;
  for (int off = 1; off < 1024; off <<= 1) {
    int t = (threadIdx.x >= (unsigned)off) ? sd[threadIdx.x - off] : 0;
    __syncthreads();
    sum += t;
    sd[threadIdx.x] = sum;
    __syncthreads();
  }
  if (threadIdx.x < (unsigned)nChunks) chunkOff[threadIdx.x] = sum - v;
}

__global__ void scan3_kernel(const int* __restrict__ ex, const int* __restrict__ chunkOff,
    const int* __restrict__ chunkSum, int* __restrict__ rp, int n, int nChunks) {
  int i = blockIdx.x * 256 + threadIdx.x;
  if (i < n) rp[i] = ex[i] + chunkOff[i >> 10];
  if (i == 0) rp[n] = chunkOff[nChunks - 1] + chunkSum[nChunks - 1];
}

__global__ void copy_kernel(const int* __restrict__ a, int* __restrict__ b, int n) {
  int i = blockIdx.x * 256 + threadIdx.x;
  if (i < n) b[i] = a[i];
}

// XCD-partitioned CSR fill (round-10) + nontemporal edge streams: the 8x
// re-read of the edge list was evicting the partition's col lines from the
// 4 MB L2 before they filled (WRITE_SIZE 65 MB). Nontemporal loads keep the
// streams out of L2 so col lines write back once.
__global__ __launch_bounds__(256) void fillx_kernel(const int* __restrict__ src,
    const int* __restrict__ dst, int* __restrict__ cursor, int* __restrict__ col,
    int n, int nAtoms) {
  const int part = blockIdx.x & 7;
  const int blkInPart = blockIdx.x >> 3;
  const int nBlkPerPart = gridDim.x >> 3;
  const int partSize = (nAtoms + 7) >> 3;
  const int lo = part * partSize;
  const int hi = min(lo + partSize, nAtoms);
  const int stride = nBlkPerPart * 256;
  for (int i = blkInPart * 256 + (int)threadIdx.x; i < n; i += stride) {
    int d = __builtin_nontemporal_load(&dst[i]);
    if (d >= lo && d < hi) {
      int s = __builtin_nontemporal_load(&src[i]);
      int p = atomicAdd(&cursor[d], 1);
      col[p] = s;
    }
  }
}

// ---- neighbor gather (round-9 structure) ----
__global__ __launch_bounds__(256) void gather_kernel(const unsigned short* __restrict__ x,
    const int* __restrict__ rp, const int* __restrict__ col,
    unsigned short* __restrict__ agg, int n) {
  int wid = (blockIdx.x * 256 + threadIdx.x) >> 6;
  int lane = threadIdx.x & 63;
  if (wid >= n) return;
  const int half = lane >> 5;
  const int l32 = lane & 31;
  const unsigned long long* xq = (const unsigned long long*)x;

  float a0, a1, a2, a3;
  {
    unsigned long long sv = xq[(size_t)wid * 32 + l32];
    if (half == 0) {
      a0 = b2f((unsigned int)(sv & 0xffffu));
      a1 = b2f((unsigned int)((sv >> 16) & 0xffffu));
      a2 = b2f((unsigned int)((sv >> 32) & 0xffffu));
      a3 = b2f((unsigned int)((sv >> 48) & 0xffffu));
    } else {
      a0 = a1 = a2 = a3 = 0.f;
    }
  }
  const int beg = rp[wid], end = rp[wid + 1];
  int j = beg;
  for (; j + 4 <= end; j += 4) {
    int c0 = col[j + half];
    int c1 = col[j + 2 + half];
    unsigned long long v0 = xq[(size_t)c0 * 32 + l32];
    unsigned long long v1 = xq[(size_t)c1 * 32 + l32];
    a0 += b2f((unsigned int)(v0 & 0xffffu)) + b2f((unsigned int)(v1 & 0xffffu));
    a1 += b2f((unsigned int)((v0 >> 16) & 0xffffu)) + b2f((unsigned int)((v1 >> 16) & 0xffffu));
    a2 += b2f((unsigned int)((v0 >> 32) & 0xffffu)) + b2f((unsigned int)((v1 >> 32) & 0xffffu));
    a3 += b2f((unsigned int)((v0 >> 48) & 0xffffu)) + b2f((unsigned int)((v1 >> 48) & 0xffffu));
  }
  if (j + 2 <= end) {
    int c0 = col[j + half];
    unsigned long long v0 = xq[(size_t)c0 * 32 + l32];
    a0 += b2f((unsigned int)(v0 & 0xffffu));
    a1 += b2f((unsigned int)((v0 >> 16) & 0xffffu));
    a2 += b2f((unsigned int)((v0 >> 32) & 0xffffu));
    a3 += b2f((unsigned int)((v0 >> 48) & 0xffffu));
    j += 2;
  }
  if (j < end && half == 0) {
    int c0 = col[j];
    unsigned long long v0 = xq[(size_t)c0 * 32 + l32];
    a0 += b2f((unsigned int)(v0 & 0xffffu));
    a1 += b2f((unsigned int)((v0 >> 16) & 0xffffu));
    a2 += b2f((unsigned int)((v0 >> 32) & 0xffffu));
    a3 += b2f((unsigned int)((v0 >> 48) & 0xffffu));
  }
  a0 += __shfl_xor(a0, 32, 64);
  a1 += __shfl_xor(a1, 32, 64);
  a2 += __shfl_xor(a2, 32, 64);
  a3 += __shfl_xor(a3, 32, 64);
  if (half == 0) {
    unsigned long long r = (unsigned long long)f2b(a0) |
                           ((unsigned long long)f2b(a1) << 16) |
                           ((unsigned long long)f2b(a2) << 32) |
                           ((unsigned long long)f2b(a3) << 48);
    ((unsigned long long*)agg)[(size_t)wid * 32 + l32] = r;
  }
}

// ---- GEMM1: H = relu(A @ W1 + b1) ----
__global__ __launch_bounds__(256) void gemm1_kernel(
    const unsigned short* __restrict__ A, const unsigned short* __restrict__ W1T,
    const float* __restrict__ b1, unsigned short* __restrict__ H, int n) {
  const int wave = threadIdx.x >> 6;
  const int lane = threadIdx.x & 63;
  const int lr = lane & 15, lg = lane >> 4;
  const int rowBase = blockIdx.x * 64 + wave * 16;
  short8 a[4];
#pragma unroll
  for (int kt = 0; kt < 4; ++kt)
    a[kt] = *(const short8*)(A + (size_t)(rowBase + lr) * FEAT + kt * 32 + lg * 8);
  f32x4 acc[8];
#pragma unroll
  for (int ct = 0; ct < 8; ++ct) {
    const unsigned short* bp = W1T + (size_t)(ct * 16 + lr) * FEAT + lg * 8;
    f32x4 c = {0.f, 0.f, 0.f, 0.f};
    c = mfma16(a[0], *(const short8*)(bp), c);
    c = mfma16(a[1], *(const short8*)(bp + 32), c);
    c = mfma16(a[2], *(const short8*)(bp + 64), c);
    c = mfma16(a[3], *(const short8*)(bp + 96), c);
    acc[ct] = c;
  }
#pragma unroll
  for (int ct = 0; ct < 8; ++ct) {
    const int c = ct * 16 + lr;
    const float bias = b1[c];
#pragma unroll
    for (int j = 0; j < 4; ++j) {
      const int row = rowBase + lg * 4 + j;
      if (row < n) {
        float v = acc[ct][j] + bias;
        H[(size_t)row * FEAT + c] = f2b(v > 0.f ? v : 0.f);
      }
    }
  }
}

// ================= LDS-staged GEMM2 passes =================
// 128-col slices (32 KB stage) -> 4 blocks/CU (vs round-10's 64 KB/2 blocks):
// statT was VALU-bound at 64% busy with 36% idle bubbles; doubling resident
// waves fills them. Softmax in exp2 domain (W2T/b2 pre-scaled by log2e).

// ---- statT: partial per-row softmax stats (log2 domain) over a 128-col slice ----
__global__ __launch_bounds__(512) void statT_kernel(
    const unsigned short* __restrict__ H, const unsigned short* __restrict__ W2T,
    const float* __restrict__ b2, float* __restrict__ pm, float* __restrict__ ps,
    int nPad) {
  __shared__ short8 ldsB[2048];   // 32 KB
  __shared__ float ldsBias[128];
  const int wave = threadIdx.x >> 6;
  const int lane = threadIdx.x & 63;
  const int lr = lane & 15, lg = lane >> 4;
  const int nRowBlk = nPad >> 8;
  const int rowBlk = blockIdx.x % nRowBlk;
  const int colBlk = blockIdx.x / nRowBlk;   // [0,16)
  const int rowBase = rowBlk * 256 + wave * 32;
  const int colBase = colBlk * 128;

#pragma unroll
  for (int r = 0; r < 4; ++r) {
    const int p = r * 8 + wave;
    const int ct = p >> 2, q = p & 3;
    ldsB[p * 64 + lane] =
        *(const short8*)(W2T + (size_t)(colBase + ct * 16 + lr) * FEAT + (q * 4 + lg) * 8);
  }
  if (threadIdx.x < 128) ldsBias[threadIdx.x] = b2[colBase + threadIdx.x] * LOG2E;

  short8 a[2][4];
#pragma unroll
  for (int g = 0; g < 2; ++g)
#pragma unroll
    for (int kt = 0; kt < 4; ++kt)
      a[g][kt] = *(const short8*)(H + (size_t)(rowBase + g * 16 + lr) * FEAT + kt * 32 + lg * 8);
  __syncthreads();

  float m[2][4], s[2][4];
#pragma unroll
  for (int g = 0; g < 2; ++g)
#pragma unroll
    for (int j = 0; j < 4; ++j) { m[g][j] = -1e30f; s[g][j] = 0.f; }

#pragma unroll 4
  for (int ct = 0; ct < 8; ++ct) {
    short8 q0 = ldsB[(ct * 4 + 0) * 64 + lane];
    short8 q1 = ldsB[(ct * 4 + 1) * 64 + lane];
    short8 q2 = ldsB[(ct * 4 + 2) * 64 + lane];
    short8 q3 = ldsB[(ct * 4 + 3) * 64 + lane];
    f32x4 c0 = {0.f, 0.f, 0.f, 0.f};
    f32x4 c1 = {0.f, 0.f, 0.f, 0.f};
    c0 = mfma16(a[0][0], q0, c0);
    c1 = mfma16(a[1][0], q0, c1);
    c0 = mfma16(a[0][1], q1, c0);
    c1 = mfma16(a[1][1], q1, c1);
    c0 = mfma16(a[0][2], q2, c0);
    c1 = mfma16(a[1][2], q2, c1);
    c0 = mfma16(a[0][3], q3, c0);
    c1 = mfma16(a[1][3], q3, c1);
    const float bs = ldsBias[ct * 16 + lr];
    // d = (logit*log2e) - m ; needed for exp2 anyway, max-tree gives the check
    float d0[4], d1[4];
#pragma unroll
    for (int j = 0; j < 4; ++j) {
      d0[j] = c0[j] + bs - m[0][j];
      d1[j] = c1[j] + bs - m[1][j];
    }
    float dmax = fmaxf(fmaxf(fmaxf(d0[0], d0[1]), fmaxf(d0[2], d0[3])),
                       fmaxf(fmaxf(d1[0], d1[1]), fmaxf(d1[2], d1[3])));
    if (__any(dmax > 12.f)) {
#pragma unroll
      for (int j = 0; j < 4; ++j) {
        float e0 = d0[j] + m[0][j], e1 = d1[j] + m[1][j];
        float nm0 = fmaxf(m[0][j], e0);
        s[0][j] = s[0][j] * exp2x(m[0][j] - nm0) + exp2x(e0 - nm0);
        m[0][j] = nm0;
        float nm1 = fmaxf(m[1][j], e1);
        s[1][j] = s[1][j] * exp2x(m[1][j] - nm1) + exp2x(e1 - nm1);
        m[1][j] = nm1;
      }
    } else {
#pragma unroll
      for (int j = 0; j < 4; ++j) {
        s[0][j] += exp2x(d0[j]);
        s[1][j] += exp2x(d1[j]);
      }
    }
  }
  // merge across the 16 lr lanes (distinct col sub-slices of the same rows)
#pragma unroll
  for (int g = 0; g < 2; ++g)
#pragma unroll
    for (int j = 0; j < 4; ++j) {
#pragma unroll
      for (int d = 1; d < 16; d <<= 1) {
        float om = __shfl_xor(m[g][j], d, 64);
        float os = __shfl_xor(s[g][j], d, 64);
        float nm = fmaxf(m[g][j], om);
        s[g][j] = s[g][j] * exp2x(m[g][j] - nm) + os * exp2x(om - nm);
        m[g][j] = nm;
      }
    }
  if (lr == 0) {
#pragma unroll
    for (int g = 0; g < 2; ++g)
#pragma unroll
      for (int j = 0; j < 4; ++j) {
        const int row = rowBase + g * 16 + lg * 4 + j;
        pm[(size_t)colBlk * nPad + row] = m[g][j];
        ps[(size_t)colBlk * nPad + row] = s[g][j];
      }
  }
}

// ---- mergeT: T[r] = M + log2(sum_k s_k * 2^(m_k - M)) over the 16 col-slices ----
__global__ void mergeT_kernel(const float* __restrict__ pm, const float* __restrict__ ps,
                              float* __restrict__ T, int nPad) {
  int r = blockIdx.x * 256 + threadIdx.x;
  if (r < nPad) {
    float M = pm[r];
#pragma unroll
    for (int k = 1; k < 16; ++k) M = fmaxf(M, pm[(size_t)k * nPad + r]);
    float S = 0.f;
#pragma unroll
    for (int k = 0; k < 16; ++k) S += ps[(size_t)k * nPad + r] * exp2x(pm[(size_t)k * nPad + r] - M);
    T[r] = M + __log2f(S);
  }
}

// ---- fpacc: recompute logits, fp_partial[c] += sum_r 2^(l'[r,c] - T[r]) ----
__global__ __launch_bounds__(512) void fpacc_kernel(
    const unsigned short* __restrict__ H, const unsigned short* __restrict__ W2T,
    const float* __restrict__ b2, const float* __restrict__ T,
    float* __restrict__ partials, int n, int nPad) {
  __shared__ short8 ldsB[2048];   // 32 KB
  __shared__ float ldsBias[128];
  __shared__ float fp_w[8][128];  // 4 KB
  const int wave = threadIdx.x >> 6;
  const int lane = threadIdx.x & 63;
  const int lr = lane & 15, lg = lane >> 4;
  const int nRowBlk = nPad >> 8;
  const int rowBlk = blockIdx.x % nRowBlk;
  const int colBlk = blockIdx.x / nRowBlk;
  const int rowBase = rowBlk * 256 + wave * 32;
  const int colBase = colBlk * 128;

#pragma unroll
  for (int r = 0; r < 4; ++r) {
    const int p = r * 8 + wave;
    const int ct = p >> 2, q = p & 3;
    ldsB[p * 64 + lane] =
        *(const short8*)(W2T + (size_t)(colBase + ct * 16 + lr) * FEAT + (q * 4 + lg) * 8);
  }
  if (threadIdx.x < 128) ldsBias[threadIdx.x] = b2[colBase + threadIdx.x] * LOG2E;

  short8 a[2][4];
#pragma unroll
  for (int g = 0; g < 2; ++g)
#pragma unroll
    for (int kt = 0; kt < 4; ++kt)
      a[g][kt] = *(const short8*)(H + (size_t)(rowBase + g * 16 + lr) * FEAT + kt * 32 + lg * 8);
  float Tq[2][4];
#pragma unroll
  for (int g = 0; g < 2; ++g)
#pragma unroll
    for (int j = 0; j < 4; ++j) {
      const int row = rowBase + g * 16 + lg * 4 + j;
      Tq[g][j] = (row < n) ? T[row] : 1e30f;  // pad rows contribute 0
    }
  __syncthreads();

#pragma unroll 4
  for (int ct = 0; ct < 8; ++ct) {
    short8 q0 = ldsB[(ct * 4 + 0) * 64 + lane];
    short8 q1 = ldsB[(ct * 4 + 1) * 64 + lane];
    short8 q2 = ldsB[(ct * 4 + 2) * 64 + lane];
    short8 q3 = ldsB[(ct * 4 + 3) * 64 + lane];
    f32x4 c0 = {0.f, 0.f, 0.f, 0.f};
    f32x4 c1 = {0.f, 0.f, 0.f, 0.f};
    c0 = mfma16(a[0][0], q0, c0);
    c1 = mfma16(a[1][0], q0, c1);
    c0 = mfma16(a[0][1], q1, c0);
    c1 = mfma16(a[1][1], q1, c1);
    c0 = mfma16(a[0][2], q2, c0);
    c1 = mfma16(a[1][2], q2, c1);
    c0 = mfma16(a[0][3], q3, c0);
    c1 = mfma16(a[1][3], q3, c1);
    const float bs = ldsBias[ct * 16 + lr];
    float p = exp2x(c0[0] + (bs - Tq[0][0])) + exp2x(c0[1] + (bs - Tq[0][1])) +
              exp2x(c0[2] + (bs - Tq[0][2])) + exp2x(c0[3] + (bs - Tq[0][3])) +
              exp2x(c1[0] + (bs - Tq[1][0])) + exp2x(c1[1] + (bs - Tq[1][1])) +
              exp2x(c1[2] + (bs - Tq[1][2])) + exp2x(c1[3] + (bs - Tq[1][3]));
    p += __shfl_xor(p, 16, 64);
    p += __shfl_xor(p, 32, 64);
    if (lg == 0) fp_w[wave][ct * 16 + lr] = p;
  }
  __syncthreads();
  if (threadIdx.x < 128) {
    float sum = 0.f;
#pragma unroll
    for (int w = 0; w < 8; ++w) sum += fp_w[w][threadIdx.x];
    partials[(size_t)rowBlk * FPL + colBase + threadIdx.x] += sum;
  }
}

__global__ void reduce_kernel(const float* __restrict__ partials, float* __restrict__ out, int nPart) {
  int c = blockIdx.x * 256 + threadIdx.x;
  if (c < FPL) {
    float s = 0.f;
    for (int p = 0; p < nPart; ++p) s += partials[(size_t)p * FPL + c];
    out[c] = s;
  }
}

extern "C" void kernel_launch(void* const* d_in, const int* in_sizes, int n_in,
                              void* d_out, int out_size, void* d_ws, size_t ws_size,
                              hipStream_t stream) {
  const float* atoms = (const float*)d_in[0];
  const float* W1 = (const float*)d_in[1];
  const float* b1 = (const float*)d_in[2];
  const float* W2 = (const float*)d_in[3];
  const float* b2 = (const float*)d_in[4];
  const int* esrc = (const int*)d_in[5];
  const int* edst = (const int*)d_in[6];
  const int nAtoms = in_sizes[0] / FEAT;
  const int nEdges = in_sizes[5];
  if (nAtoms <= 0) return;

  const int g2Blocks = (nAtoms + 255) / 256;  // 256-row tiles for statT/fpacc
  const int nPad = g2Blocks * 256;
  const int g1Blocks = nPad / 64;
  const int nChunks = (nAtoms + 1023) / 1024;

  size_t off = 0;
  auto alloc = [&](size_t bytes) -> void* {
    void* p = (char*)d_ws + off;
    off += (bytes + 255) & ~(size_t)255;
    return p;
  };
  unsigned short* P = (unsigned short*)alloc((size_t)nPad * FEAT * 2);
  unsigned short* Q = (unsigned short*)alloc((size_t)nPad * FEAT * 2);
  unsigned short* W1T = (unsigned short*)alloc((size_t)FEAT * FEAT * 2);
  unsigned short* W2T = (unsigned short*)alloc((size_t)FEAT * FPL * 2);
  int* counts = (int*)alloc((size_t)nAtoms * 4);
  int* cursor = (int*)alloc((size_t)nAtoms * 4);
  int* rp = (int*)alloc(((size_t)nAtoms + 1) * 4);
  int* ex = (int*)alloc((size_t)nAtoms * 4);
  int* chunkSum = (int*)alloc((size_t)nChunks * 4);
  int* chunkOff = (int*)alloc((size_t)nChunks * 4);
  int* col = (int*)alloc((size_t)nEdges * 4);
  float* pm = (float*)alloc((size_t)16 * nPad * 4);
  float* ps = (float*)alloc((size_t)16 * nPad * 4);
  float* Trow = (float*)alloc((size_t)nPad * 4);
  float* partials = (float*)alloc((size_t)g2Blocks * FPL * 4);

  hipMemsetAsync(counts, 0, (size_t)nAtoms * 4, stream);
  hipMemsetAsync(partials, 0, (size_t)g2Blocks * FPL * 4, stream);
  hipMemsetAsync(P + (size_t)nAtoms * FEAT, 0, (size_t)(nPad - nAtoms) * FEAT * 2, stream);
  hipMemsetAsync(Q + (size_t)nAtoms * FEAT, 0, (size_t)(nPad - nAtoms) * FEAT * 2, stream);

  const int n2 = in_sizes[0] / 2;
  cvt_kernel<<<(n2 + 255) / 256, 256, 0, stream>>>(atoms, P, n2);
  cvtT_kernel<<<(FEAT * FEAT + 255) / 256, 256, 0, stream>>>(W1, W1T, FEAT, FEAT, 1.0f);
  cvtT_kernel<<<(FEAT * FPL + 255) / 256, 256, 0, stream>>>(W2, W2T, FEAT, FPL, LOG2E);
  count_kernel<<<(nEdges + 255) / 256, 256, 0, stream>>>(edst, counts, nEdges);
  scan1_kernel<<<nChunks, 1024, 0, stream>>>(counts, ex, chunkSum, nAtoms);
  scan2_kernel<<<1, 1024, 0, stream>>>(chunkSum, chunkOff, nChunks);
  scan3_kernel<<<(nAtoms + 255) / 256, 256, 0, stream>>>(ex, chunkOff, chunkSum, rp, nAtoms, nChunks);
  copy_kernel<<<(nAtoms + 255) / 256, 256, 0, stream>>>(rp, cursor, nAtoms);
  fillx_kernel<<<1024, 256, 0, stream>>>(esrc, edst, cursor, col, nEdges, nAtoms);

  unsigned short* x = P;
  unsigned short* y = Q;
  for (int step = 0; step < 3; ++step) {
    gather_kernel<<<(nAtoms + 3) / 4, 256, 0, stream>>>(x, rp, col, y, nAtoms);
    gemm1_kernel<<<g1Blocks, 256, 0, stream>>>(y, W1T, b1, y, nAtoms);
    statT_kernel<<<g2Blocks * 16, 512, 0, stream>>>(y, W2T, b2, pm, ps, nPad);
    mergeT_kernel<<<(nPad + 255) / 256, 256, 0, stream>>>(pm, ps, Trow, nPad);
    fpacc_kernel<<<g2Blocks * 16, 512, 0, stream>>>(y, W2T, b2, Trow, partials, nAtoms, nPad);
    unsigned short* t = x; x = y; y = t;
  }
  reduce_kernel<<<(FPL + 255) / 256, 256, 0, stream>>>(partials, (float*)d_out, g2Blocks);
}